// Round 16
// baseline (685.896 us; speedup 1.0000x reference)
//
#include <hip/hip_runtime.h>

// x [T,B,NI] fp32, W [NO,NI] fp32 -> spk_rec [T,B,NO], mem_rec [T,B,NO]
// VERIFIED bit-exact (rounds 9-15): cur = per-element fold of 4 ascending-k
// FMA chains over K-blocks [512x4], combined left-assoc ((c0+c1)+c2)+c3;
// scan = fp32 separate-rounding: reset=(mem>1); mem=((0.9f*mem)+cur)-reset.
// Round 16: staging via global_load_lds (async DMA, no VGPR round-trip, no
// transpose ds_writes). Row-major LDS with XOR slot swizzle:
//   LDS As[r][p] holds X[m0+r][k0 + 4*(p ^ (r&7)) .. +3]
// (source pre-swizzled per lane; read XORs the slot; bijective per row).
#define T_STEPS 100
#define BATCH   128
#define NI      2048
#define NO      1024
#define M_TOT   (T_STEPS * BATCH)        // 12800
#define TOTAL   (T_STEPS * BATCH * NO)   // 13107200 per output tensor
#define BNTOT   (BATCH * NO)             // 131072
#define X_ELEMS (M_TOT * NI)             // 26214400

#define BMf 128
#define BNf 128
#define BKf 32
#define KSL 8            // float4 k-slots per LDS row (BKf/4)
#define NXB (NO / BNf)   // 8    n-blocks
#define NYB (M_TOT/BMf)  // 100  m-blocks
// grid = NXB * NYB * 4 chains = 3200; per XCD 400 = 8n x 50 (chain,m) pairs

__device__ __forceinline__ void glds16(const float* g, float* l) {
    __builtin_amdgcn_global_load_lds(
        (const __attribute__((address_space(1))) void*)g,
        (__attribute__((address_space(3))) void*)l, 16, 0, 0);
}

__global__ __launch_bounds__(256) void gemm_chain512(const float* __restrict__ X,
                                                     const float* __restrict__ W,
                                                     float* __restrict__ p0,
                                                     float* __restrict__ p1,
                                                     float* __restrict__ p2,
                                                     float* __restrict__ p3) {
    __shared__ float As[BMf][32];   // 128 rows x 128B, swizzled slots
    __shared__ float Bs[BNf][32];

    // XCD-aware decomposition: xcd owns 50 (chain,m) pairs, n fastest.
    const int orig  = blockIdx.x;
    const int xcd   = orig & 7;
    const int q     = orig >> 3;        // 0..399
    const int n0    = (q & 7) * BNf;
    const int sq    = q >> 3;           // 0..49
    const int pp    = xcd * 50 + sq;    // 0..399
    const int chain = pp / 100;         // 0..3
    const int m0    = (pp - chain * 100) * BMf;
    const int kbase = chain * 512;
    float* out = (chain == 0) ? p0 : (chain == 1) ? p1 : (chain == 2) ? p2 : p3;

    const int tid = threadIdx.x;
    const int tx  = tid & 15;        // cols n0 + tx + 16*j
    const int ty  = tid >> 4;        // rows m0 + ty + 16*i   (0..15)
    const int w   = tid >> 6;        // wave 0..3
    const int l   = tid & 63;
    const int lr  = l >> 3;          // DMA row-within-8group 0..7
    const int swz = (l & 7) ^ lr;    // pre-swizzled source k-slot

    // per-lane DMA source pointers (advance by k inside loop)
    const float* pA = X + (size_t)(m0 + w * 32 + lr) * NI + kbase + swz * 4;
    const float* pB = W + (size_t)(n0 + w * 32 + lr) * NI + kbase + swz * 4;

    const int ty7 = ty & 7;
    const int tx7 = tx & 7;

    float acc[8][8] = {};

    #pragma unroll 1
    for (int k0 = 0; k0 < 512; k0 += BKf) {
        // ---- stage: 8 async DMA instrs per wave (4 A-rows-of-8, 4 B) ----
        #pragma unroll
        for (int c = 0; c < 4; ++c) {
            glds16(pA + k0 + (size_t)c * 8 * NI, &As[w * 32 + c * 8][0]);
            glds16(pB + k0 + (size_t)c * 8 * NI, &Bs[w * 32 + c * 8][0]);
        }
        __syncthreads();   // drains vmcnt (incl. global_load_lds)

        // ---- compute: ascending k, FMA, one accumulator per element ----
        #pragma unroll
        for (int ss = 0; ss < KSL; ++ss) {
            const int oA = (ss ^ ty7) << 2;   // float offset within row
            const int oB = (ss ^ tx7) << 2;
            float4 a4[8];
            #pragma unroll
            for (int i = 0; i < 8; ++i)
                a4[i] = *reinterpret_cast<const float4*>(&As[ty + 16 * i][oA]);
            #pragma unroll
            for (int j = 0; j < 8; ++j) {
                const float4 b4 = *reinterpret_cast<const float4*>(&Bs[tx + 16 * j][oB]);
                #pragma unroll
                for (int i = 0; i < 8; ++i) {
                    acc[i][j] = __fmaf_rn(a4[i].x, b4.x, acc[i][j]);
                    acc[i][j] = __fmaf_rn(a4[i].y, b4.y, acc[i][j]);
                    acc[i][j] = __fmaf_rn(a4[i].z, b4.z, acc[i][j]);
                    acc[i][j] = __fmaf_rn(a4[i].w, b4.w, acc[i][j]);
                }
            }
        }
        __syncthreads();
    }

    // ---- epilogue: store chain partial (scalar, stride-16 cols) ----
    #pragma unroll
    for (int i = 0; i < 8; ++i) {
        const size_t rowbase = (size_t)(m0 + ty + 16 * i) * NO + n0;
        #pragma unroll
        for (int j = 0; j < 8; ++j)
            out[rowbase + tx + 16 * j] = acc[i][j];
    }
}

// ---- fused fold + LIF scan: cur = ((p0+p1)+p2)+p3 (exact ref order), then
// scan. p0 lives in the spk slot, p1 in the mem slot (same-thread RAW only).
__global__ __launch_bounds__(256) void fold_scan(float* __restrict__ spk,
                                                 float* __restrict__ memf,
                                                 const float* __restrict__ p2,
                                                 const float* __restrict__ p3) {
    const int idx = (blockIdx.x * blockDim.x + threadIdx.x) * 4;
    float4 mem = make_float4(0.f, 0.f, 0.f, 0.f);
    for (int t = 0; t < T_STEPS; ++t) {
        const size_t i = (size_t)t * BNTOT + idx;
        const float4 c0 = *reinterpret_cast<const float4*>(&spk[i]);
        const float4 c1 = *reinterpret_cast<const float4*>(&memf[i]);
        const float4 c2 = *reinterpret_cast<const float4*>(&p2[i]);
        const float4 c3 = *reinterpret_cast<const float4*>(&p3[i]);
        float4 spkv;
        #define STEP(c)                                                     \
        {                                                                   \
            const float cur = __fadd_rn(__fadd_rn(__fadd_rn(c0.c, c1.c),    \
                                                  c2.c), c3.c);             \
            const float reset = (mem.c > 1.0f) ? 1.0f : 0.0f;               \
            float tmp = __fmul_rn(0.9f, mem.c);                             \
            tmp = __fadd_rn(tmp, cur);                                      \
            mem.c = __fsub_rn(tmp, reset);                                  \
            spkv.c = (mem.c > 1.0f) ? 1.0f : 0.0f;                          \
        }
        STEP(x) STEP(y) STEP(z) STEP(w)
        #undef STEP
        *reinterpret_cast<float4*>(&spk[i])  = spkv;
        *reinterpret_cast<float4*>(&memf[i]) = mem;
    }
}

// ============== fallback path (round-13 single-kernel, proven) ==============
#define BMs 64
#define BKs2 32
#define LDAs (BMs + 4)
#define LDBs (BNf + 4)
#define NYBs (M_TOT / BMs)   // 200
#define YPXs (NYBs / 8)      // 25

__global__ __launch_bounds__(256) void gemm_512fold(const float* __restrict__ X,
                                                    const float* __restrict__ W,
                                                    float* __restrict__ curOut) {
    __shared__ float As[BKs2][LDAs];
    __shared__ float Bs[BKs2][LDBs];
    const int orig = blockIdx.x;
    const int k_x  = orig & 7;
    const int q    = orig >> 3;
    const int m0   = (k_x * YPXs + (q >> 3)) * BMs;
    const int n0   = (q & 7) * BNf;
    const int tid = threadIdx.x;
    const int tx  = tid & 15;
    const int ty  = tid >> 4;
    const int ar = tid >> 2;
    const int ak = (tid & 3) * 4;
    const int br = tid >> 1;
    const int bk = (tid & 1) * 4;
    float ch[4][8]  = {};
    float tot[4][8] = {};
    #pragma unroll 1
    for (int k0 = 0; k0 < NI; k0 += BKs2) {
        if (k0 == 512 || k0 == 1024 || k0 == 1536) {
            #pragma unroll
            for (int i = 0; i < 4; ++i)
                #pragma unroll
                for (int j = 0; j < 8; ++j) {
                    tot[i][j] = __fadd_rn(tot[i][j], ch[i][j]);
                    ch[i][j]  = 0.0f;
                }
        }
        {
            const float4 fa0 = *reinterpret_cast<const float4*>(
                &X[(size_t)(m0 + ar) * NI + k0 + ak]);
            const float4 fa1 = *reinterpret_cast<const float4*>(
                &X[(size_t)(m0 + ar) * NI + k0 + ak + 16]);
            As[ak + 0][ar] = fa0.x;  As[ak + 1][ar] = fa0.y;
            As[ak + 2][ar] = fa0.z;  As[ak + 3][ar] = fa0.w;
            As[ak + 16][ar] = fa1.x; As[ak + 17][ar] = fa1.y;
            As[ak + 18][ar] = fa1.z; As[ak + 19][ar] = fa1.w;
            #pragma unroll
            for (int qq = 0; qq < 4; ++qq) {
                const int kb = bk + qq * 8;
                const float4 fb = *reinterpret_cast<const float4*>(
                    &W[(size_t)(n0 + br) * NI + k0 + kb]);
                Bs[kb + 0][br] = fb.x; Bs[kb + 1][br] = fb.y;
                Bs[kb + 2][br] = fb.z; Bs[kb + 3][br] = fb.w;
            }
        }
        __syncthreads();
        #pragma unroll
        for (int kk = 0; kk < BKs2; ++kk) {
            float a[4], b[8];
            *reinterpret_cast<float4*>(&a[0]) =
                *reinterpret_cast<const float4*>(&As[kk][ty * 4]);
            *reinterpret_cast<float4*>(&b[0]) =
                *reinterpret_cast<const float4*>(&Bs[kk][tx * 4]);
            *reinterpret_cast<float4*>(&b[4]) =
                *reinterpret_cast<const float4*>(&Bs[kk][64 + tx * 4]);
            #pragma unroll
            for (int i = 0; i < 4; ++i)
                #pragma unroll
                for (int j = 0; j < 8; ++j)
                    ch[i][j] = __fmaf_rn(a[i], b[j], ch[i][j]);
        }
        __syncthreads();
    }
    #pragma unroll
    for (int i = 0; i < 4; ++i) {
        const size_t rowbase = (size_t)(m0 + ty * 4 + i) * NO + n0;
        #pragma unroll
        for (int h = 0; h < 2; ++h) {
            float4 v;
            v.x = __fadd_rn(tot[i][h * 4 + 0], ch[i][h * 4 + 0]);
            v.y = __fadd_rn(tot[i][h * 4 + 1], ch[i][h * 4 + 1]);
            v.z = __fadd_rn(tot[i][h * 4 + 2], ch[i][h * 4 + 2]);
            v.w = __fadd_rn(tot[i][h * 4 + 3], ch[i][h * 4 + 3]);
            *reinterpret_cast<float4*>(&curOut[rowbase + h * 64 + tx * 4]) = v;
        }
    }
}

__global__ __launch_bounds__(256) void lif_scan(float* __restrict__ spk,
                                                float* __restrict__ memf) {
    const int idx = (blockIdx.x * blockDim.x + threadIdx.x) * 4;
    float4 mem = make_float4(0.f, 0.f, 0.f, 0.f);
    for (int t = 0; t < T_STEPS; ++t) {
        const size_t i = (size_t)t * BNTOT + idx;
        const float4 cur = *reinterpret_cast<const float4*>(&memf[i]);
        float4 spkv;
        #define STEP(c)                                                   \
        {                                                                 \
            const float reset = (mem.c > 1.0f) ? 1.0f : 0.0f;             \
            float tmp = __fmul_rn(0.9f, mem.c);                           \
            tmp = __fadd_rn(tmp, cur.c);                                  \
            mem.c = __fsub_rn(tmp, reset);                                \
            spkv.c = (mem.c > 1.0f) ? 1.0f : 0.0f;                        \
        }
        STEP(x) STEP(y) STEP(z) STEP(w)
        #undef STEP
        *reinterpret_cast<float4*>(&spk[i])  = spkv;
        *reinterpret_cast<float4*>(&memf[i]) = mem;
    }
}

extern "C" void kernel_launch(void* const* d_in, const int* in_sizes, int n_in,
                              void* d_out, int out_size, void* d_ws, size_t ws_size,
                              hipStream_t stream) {
    const float* X;
    const float* W;
    if (in_sizes[0] == X_ELEMS) { X = (const float*)d_in[0]; W = (const float*)d_in[1]; }
    else                        { X = (const float*)d_in[1]; W = (const float*)d_in[0]; }

    float* spk  = (float*)d_out;     // [T,B,NO]
    float* memf = spk + TOTAL;       // [T,B,NO]

    if (ws_size >= (size_t)2 * TOTAL * sizeof(float)) {
        // K-split path: chains c0->spk slot, c1->mem slot, c2/c3 -> workspace
        float* p2 = (float*)d_ws;
        float* p3 = p2 + TOTAL;
        gemm_chain512<<<4 * NXB * NYB, 256, 0, stream>>>(X, W, spk, memf, p2, p3);
        fold_scan<<<BNTOT / 4 / 256, 256, 0, stream>>>(spk, memf, p2, p3);
    } else {
        // fallback: proven round-13 path
        gemm_512fold<<<NXB * NYBs, 256, 0, stream>>>(X, W, memf);
        lif_scan<<<BNTOT / 4 / 256, 256, 0, stream>>>(spk, memf);
    }
}

// Round 17
// 659.039 us; speedup vs baseline: 1.0408x; 1.0408x over previous
//
#include <hip/hip_runtime.h>

// x [T,B,NI] fp32, W [NO,NI] fp32 -> spk_rec [T,B,NO], mem_rec [T,B,NO]
// VERIFIED bit-exact (rounds 9-16): cur = per-element fold of 4 ascending-k
// FMA chains over K-blocks [512x4], combined left-assoc ((c0+c1)+c2)+c3;
// scan = fp32 separate-rounding: reset=(mem>1); mem=((0.9f*mem)+cur)-reset.
// Round 17: K-split GEMM, 128x128 tile, 512 threads (4m x 8n per thread):
// same per-thread profile as the best round (R14) but 32 waves/CU occupancy.
#define T_STEPS 100
#define BATCH   128
#define NI      2048
#define NO      1024
#define M_TOT   (T_STEPS * BATCH)        // 12800
#define TOTAL   (T_STEPS * BATCH * NO)   // 13107200 per output tensor
#define BNTOT   (BATCH * NO)             // 131072
#define X_ELEMS (M_TOT * NI)             // 26214400

#define BMf 128
#define BNf 128
#define BKf 32
#define LDT 132          // padded LDS row stride (floats)
#define NXB (NO / BNf)   // 8    n-blocks
#define NYB (M_TOT/BMf)  // 100  m-blocks
// grid = 4 chains * NYB * NXB = 3200 blocks of 512 threads

__global__ __launch_bounds__(512) void gemm_chain512(const float* __restrict__ X,
                                                     const float* __restrict__ W,
                                                     float* __restrict__ p0,
                                                     float* __restrict__ p1,
                                                     float* __restrict__ p2,
                                                     float* __restrict__ p3) {
    __shared__ float As[BKf][LDT];   // transposed: As[k][m]
    __shared__ float Bs[BKf][LDT];   // transposed: Bs[k][n]

    // XCD-aware decomposition: xcd owns 50 (chain,m) pairs, n fastest.
    const int orig  = blockIdx.x;
    const int xcd   = orig & 7;
    const int q     = orig >> 3;        // 0..399
    const int n0    = (q & 7) * BNf;
    const int sq    = q >> 3;           // 0..49
    const int pp    = xcd * 50 + sq;    // 0..399
    const int chain = pp / 100;         // 0..3
    const int m0    = (pp - chain * 100) * BMf;
    const int kbase = chain * 512;
    float* out = (chain == 0) ? p0 : (chain == 1) ? p1 : (chain == 2) ? p2 : p3;

    const int tid = threadIdx.x;
    const int tx  = tid & 15;        // cols n0 + tx*4 + j  and  +64
    const int ty  = tid >> 4;        // 0..31: rows m0 + ty*4 + i

    const int sr = tid >> 2;         // staging row 0..127 (A and B)
    const int sk = (tid & 3) * 4;    // staging k base: quads sk, sk+16

    float ch[4][8] = {};   // the 512-chain accumulators (ascending k, FMA)

    #pragma unroll 1
    for (int k0 = kbase; k0 < kbase + 512; k0 += BKf) {
        // ---- stage K-slab (transposed): 2 float4 each from X and W ----
        {
            const float4 fa0 = *reinterpret_cast<const float4*>(
                &X[(size_t)(m0 + sr) * NI + k0 + sk]);
            const float4 fa1 = *reinterpret_cast<const float4*>(
                &X[(size_t)(m0 + sr) * NI + k0 + sk + 16]);
            As[sk + 0][sr] = fa0.x;  As[sk + 1][sr] = fa0.y;
            As[sk + 2][sr] = fa0.z;  As[sk + 3][sr] = fa0.w;
            As[sk + 16][sr] = fa1.x; As[sk + 17][sr] = fa1.y;
            As[sk + 18][sr] = fa1.z; As[sk + 19][sr] = fa1.w;
            const float4 fb0 = *reinterpret_cast<const float4*>(
                &W[(size_t)(n0 + sr) * NI + k0 + sk]);
            const float4 fb1 = *reinterpret_cast<const float4*>(
                &W[(size_t)(n0 + sr) * NI + k0 + sk + 16]);
            Bs[sk + 0][sr] = fb0.x;  Bs[sk + 1][sr] = fb0.y;
            Bs[sk + 2][sr] = fb0.z;  Bs[sk + 3][sr] = fb0.w;
            Bs[sk + 16][sr] = fb1.x; Bs[sk + 17][sr] = fb1.y;
            Bs[sk + 18][sr] = fb1.z; Bs[sk + 19][sr] = fb1.w;
        }
        __syncthreads();

        // ---- compute: ascending k, FMA, one accumulator per element ----
        #pragma unroll
        for (int kk = 0; kk < BKf; ++kk) {
            float a[4], b[8];
            *reinterpret_cast<float4*>(&a[0]) =
                *reinterpret_cast<const float4*>(&As[kk][ty * 4]);
            *reinterpret_cast<float4*>(&b[0]) =
                *reinterpret_cast<const float4*>(&Bs[kk][tx * 4]);
            *reinterpret_cast<float4*>(&b[4]) =
                *reinterpret_cast<const float4*>(&Bs[kk][64 + tx * 4]);
            #pragma unroll
            for (int i = 0; i < 4; ++i)
                #pragma unroll
                for (int j = 0; j < 8; ++j)
                    ch[i][j] = __fmaf_rn(a[i], b[j], ch[i][j]);
        }
        __syncthreads();
    }

    // ---- epilogue: store chain partial, float4 stores ----
    #pragma unroll
    for (int i = 0; i < 4; ++i) {
        const size_t rowbase = (size_t)(m0 + ty * 4 + i) * NO + n0;
        #pragma unroll
        for (int h = 0; h < 2; ++h) {
            float4 v;
            v.x = ch[i][h * 4 + 0]; v.y = ch[i][h * 4 + 1];
            v.z = ch[i][h * 4 + 2]; v.w = ch[i][h * 4 + 3];
            *reinterpret_cast<float4*>(&out[rowbase + h * 64 + tx * 4]) = v;
        }
    }
}

// ---- fused fold + LIF scan: cur = ((p0+p1)+p2)+p3 (exact ref order), then
// scan. p0 lives in the spk slot, p1 in the mem slot (same-thread RAW only).
__global__ __launch_bounds__(256) void fold_scan(float* __restrict__ spk,
                                                 float* __restrict__ memf,
                                                 const float* __restrict__ p2,
                                                 const float* __restrict__ p3) {
    const int idx = (blockIdx.x * blockDim.x + threadIdx.x) * 4;
    float4 mem = make_float4(0.f, 0.f, 0.f, 0.f);
    for (int t = 0; t < T_STEPS; ++t) {
        const size_t i = (size_t)t * BNTOT + idx;
        const float4 c0 = *reinterpret_cast<const float4*>(&spk[i]);
        const float4 c1 = *reinterpret_cast<const float4*>(&memf[i]);
        const float4 c2 = *reinterpret_cast<const float4*>(&p2[i]);
        const float4 c3 = *reinterpret_cast<const float4*>(&p3[i]);
        float4 spkv;
        #define STEP(c)                                                     \
        {                                                                   \
            const float cur = __fadd_rn(__fadd_rn(__fadd_rn(c0.c, c1.c),    \
                                                  c2.c), c3.c);             \
            const float reset = (mem.c > 1.0f) ? 1.0f : 0.0f;               \
            float tmp = __fmul_rn(0.9f, mem.c);                             \
            tmp = __fadd_rn(tmp, cur);                                      \
            mem.c = __fsub_rn(tmp, reset);                                  \
            spkv.c = (mem.c > 1.0f) ? 1.0f : 0.0f;                          \
        }
        STEP(x) STEP(y) STEP(z) STEP(w)
        #undef STEP
        *reinterpret_cast<float4*>(&spk[i])  = spkv;
        *reinterpret_cast<float4*>(&memf[i]) = mem;
    }
}

// ============== fallback path (round-13 single-kernel, proven) ==============
#define BMs 64
#define LDAs (BMs + 4)
#define LDBs (BNf + 4)
#define NYBs (M_TOT / BMs)   // 200
#define YPXs (NYBs / 8)      // 25

__global__ __launch_bounds__(256) void gemm_512fold(const float* __restrict__ X,
                                                    const float* __restrict__ W,
                                                    float* __restrict__ curOut) {
    __shared__ float As[BKf][LDAs];
    __shared__ float Bs[BKf][LDBs];
    const int orig = blockIdx.x;
    const int k_x  = orig & 7;
    const int q    = orig >> 3;
    const int m0   = (k_x * YPXs + (q >> 3)) * BMs;
    const int n0   = (q & 7) * BNf;
    const int tid = threadIdx.x;
    const int tx  = tid & 15;
    const int ty  = tid >> 4;
    const int ar = tid >> 2;
    const int ak = (tid & 3) * 4;
    const int br = tid >> 1;
    const int bk = (tid & 1) * 4;
    float ch[4][8]  = {};
    float tot[4][8] = {};
    #pragma unroll 1
    for (int k0 = 0; k0 < NI; k0 += BKf) {
        if (k0 == 512 || k0 == 1024 || k0 == 1536) {
            #pragma unroll
            for (int i = 0; i < 4; ++i)
                #pragma unroll
                for (int j = 0; j < 8; ++j) {
                    tot[i][j] = __fadd_rn(tot[i][j], ch[i][j]);
                    ch[i][j]  = 0.0f;
                }
        }
        {
            const float4 fa0 = *reinterpret_cast<const float4*>(
                &X[(size_t)(m0 + ar) * NI + k0 + ak]);
            const float4 fa1 = *reinterpret_cast<const float4*>(
                &X[(size_t)(m0 + ar) * NI + k0 + ak + 16]);
            As[ak + 0][ar] = fa0.x;  As[ak + 1][ar] = fa0.y;
            As[ak + 2][ar] = fa0.z;  As[ak + 3][ar] = fa0.w;
            As[ak + 16][ar] = fa1.x; As[ak + 17][ar] = fa1.y;
            As[ak + 18][ar] = fa1.z; As[ak + 19][ar] = fa1.w;
            #pragma unroll
            for (int qq = 0; qq < 4; ++qq) {
                const int kb = bk + qq * 8;
                const float4 fb = *reinterpret_cast<const float4*>(
                    &W[(size_t)(n0 + br) * NI + k0 + kb]);
                Bs[kb + 0][br] = fb.x; Bs[kb + 1][br] = fb.y;
                Bs[kb + 2][br] = fb.z; Bs[kb + 3][br] = fb.w;
            }
        }
        __syncthreads();
        #pragma unroll
        for (int kk = 0; kk < BKf; ++kk) {
            float a[4], b[8];
            *reinterpret_cast<float4*>(&a[0]) =
                *reinterpret_cast<const float4*>(&As[kk][ty * 4]);
            *reinterpret_cast<float4*>(&b[0]) =
                *reinterpret_cast<const float4*>(&Bs[kk][tx * 4]);
            *reinterpret_cast<float4*>(&b[4]) =
                *reinterpret_cast<const float4*>(&Bs[kk][64 + tx * 4]);
            #pragma unroll
            for (int i = 0; i < 4; ++i)
                #pragma unroll
                for (int j = 0; j < 8; ++j)
                    ch[i][j] = __fmaf_rn(a[i], b[j], ch[i][j]);
        }
        __syncthreads();
    }
    #pragma unroll
    for (int i = 0; i < 4; ++i) {
        const size_t rowbase = (size_t)(m0 + ty * 4 + i) * NO + n0;
        #pragma unroll
        for (int h = 0; h < 2; ++h) {
            float4 v;
            v.x = __fadd_rn(tot[i][h * 4 + 0], ch[i][h * 4 + 0]);
            v.y = __fadd_rn(tot[i][h * 4 + 1], ch[i][h * 4 + 1]);
            v.z = __fadd_rn(tot[i][h * 4 + 2], ch[i][h * 4 + 2]);
            v.w = __fadd_rn(tot[i][h * 4 + 3], ch[i][h * 4 + 3]);
            *reinterpret_cast<float4*>(&curOut[rowbase + h * 64 + tx * 4]) = v;
        }
    }
}

__global__ __launch_bounds__(256) void lif_scan(float* __restrict__ spk,
                                                float* __restrict__ memf) {
    const int idx = (blockIdx.x * blockDim.x + threadIdx.x) * 4;
    float4 mem = make_float4(0.f, 0.f, 0.f, 0.f);
    for (int t = 0; t < T_STEPS; ++t) {
        const size_t i = (size_t)t * BNTOT + idx;
        const float4 cur = *reinterpret_cast<const float4*>(&memf[i]);
        float4 spkv;
        #define STEP(c)                                                   \
        {                                                                 \
            const float reset = (mem.c > 1.0f) ? 1.0f : 0.0f;             \
            float tmp = __fmul_rn(0.9f, mem.c);                           \
            tmp = __fadd_rn(tmp, cur.c);                                  \
            mem.c = __fsub_rn(tmp, reset);                                \
            spkv.c = (mem.c > 1.0f) ? 1.0f : 0.0f;                        \
        }
        STEP(x) STEP(y) STEP(z) STEP(w)
        #undef STEP
        *reinterpret_cast<float4*>(&spk[i])  = spkv;
        *reinterpret_cast<float4*>(&memf[i]) = mem;
    }
}

extern "C" void kernel_launch(void* const* d_in, const int* in_sizes, int n_in,
                              void* d_out, int out_size, void* d_ws, size_t ws_size,
                              hipStream_t stream) {
    const float* X;
    const float* W;
    if (in_sizes[0] == X_ELEMS) { X = (const float*)d_in[0]; W = (const float*)d_in[1]; }
    else                        { X = (const float*)d_in[1]; W = (const float*)d_in[0]; }

    float* spk  = (float*)d_out;     // [T,B,NO]
    float* memf = spk + TOTAL;       // [T,B,NO]

    if (ws_size >= (size_t)2 * TOTAL * sizeof(float)) {
        // K-split path: chains c0->spk slot, c1->mem slot, c2/c3 -> workspace
        float* p2 = (float*)d_ws;
        float* p3 = p2 + TOTAL;
        gemm_chain512<<<4 * NXB * NYB, 512, 0, stream>>>(X, W, spk, memf, p2, p3);
        fold_scan<<<BNTOT / 4 / 256, 256, 0, stream>>>(spk, memf, p2, p3);
    } else {
        // fallback: proven round-13 path
        gemm_512fold<<<NXB * NYBs, 256, 0, stream>>>(X, W, memf);
        lif_scan<<<BNTOT / 4 / 256, 256, 0, stream>>>(spk, memf);
    }
}